// Round 20
// baseline (743.161 us; speedup 1.0000x reference)
//
#include <hip/hip_runtime.h>
#include <cstddef>
#include <cstdint>
#include <math.h>

// Problem constants (B=2, S=2048, D=2048, H=16, hd=128)
#define NB 2
#define NS 2048
#define ND 2048
#define NH 16
#define HD 128

typedef __attribute__((ext_vector_type(8))) short short8v;   // 8 bf16 (4 VGPR)
typedef __attribute__((ext_vector_type(4))) float float4v;   // MFMA acc

#define MFMA16(A, B, C) __builtin_amdgcn_mfma_f32_16x16x32_bf16(A, B, C, 0, 0, 0)

// Split fp32 into bf16 hi + bf16 lo (x ~= hi + lo, rel err ~2^-17).
__device__ __forceinline__ void split_bf16(float x, short& hi, short& lo) {
  unsigned u = __float_as_uint(x);
  unsigned hb = (u + 0x7FFFu + ((u >> 16) & 1u)) >> 16;
  float hif = __uint_as_float(hb << 16);
  float r = x - hif;
  unsigned ul = __float_as_uint(r);
  hi = (short)hb;
  lo = (short)((ul + 0x7FFFu + ((ul >> 16) & 1u)) >> 16);
}

__device__ __forceinline__ int pack2(short a, short b) {
  return (int)(unsigned short)a | ((int)(unsigned short)b << 16);
}

// ---------------------------------------------------------------------------
// FUSED prep kernel (validated round-15).
// ---------------------------------------------------------------------------
__global__ __launch_bounds__(256) void fused_prep_kernel(
    float2* __restrict__ tab,
    const float* __restrict__ Wqkv, short* __restrict__ wqh,
    short* __restrict__ wql,
    const float* __restrict__ Wo, short* __restrict__ woh,
    short* __restrict__ wol,
    const float* __restrict__ x, short* __restrict__ xh,
    short* __restrict__ xl) {
  __shared__ float T[32][33];
  const int tid = threadIdx.x;
  const int blk = blockIdx.x;
  if (blk < 512) {
    const int id = blk * 256 + tid;
    const int spos = id >> 6, p = id & 63;
    const float invf = powf(10000.f, -(float)p * (1.f / 64.f));
    float s, c;
    sincosf((float)spos * invf, &s, &c);
    tab[id] = make_float2(c, s);
  } else if (blk < 12800) {
    const int t = blk - 512;
    const int n0 = (t % 192) * 32, k0 = (t / 192) * 32;
    const int K = ND, N = 3 * ND;
    {
      const int r = tid >> 3, c4 = (tid & 7) << 2;
      float4 v = *(const float4*)&Wqkv[(size_t)(k0 + r) * N + n0 + c4];
      T[r][c4 + 0] = v.x;
      T[r][c4 + 1] = v.y;
      T[r][c4 + 2] = v.z;
      T[r][c4 + 3] = v.w;
    }
    __syncthreads();
    const int n = tid >> 3, k4 = (tid & 7) << 2;
    short h[4], l[4];
#pragma unroll
    for (int e = 0; e < 4; ++e) split_bf16(T[k4 + e][n], h[e], l[e]);
    const size_t off = (size_t)(n0 + n) * K + k0 + k4;
    *(int2*)&wqh[off] = make_int2(pack2(h[0], h[1]), pack2(h[2], h[3]));
    *(int2*)&wql[off] = make_int2(pack2(l[0], l[1]), pack2(l[2], l[3]));
  } else if (blk < 16896) {
    const int t = blk - 12800;
    const int n0 = (t % 64) * 32, k0 = (t / 64) * 32;
    const int K = ND, N = ND;
    {
      const int r = tid >> 3, c4 = (tid & 7) << 2;
      float4 v = *(const float4*)&Wo[(size_t)(k0 + r) * N + n0 + c4];
      T[r][c4 + 0] = v.x;
      T[r][c4 + 1] = v.y;
      T[r][c4 + 2] = v.z;
      T[r][c4 + 3] = v.w;
    }
    __syncthreads();
    const int n = tid >> 3, k4 = (tid & 7) << 2;
    short h[4], l[4];
#pragma unroll
    for (int e = 0; e < 4; ++e) split_bf16(T[k4 + e][n], h[e], l[e]);
    const size_t off = (size_t)(n0 + n) * K + k0 + k4;
    *(int2*)&woh[off] = make_int2(pack2(h[0], h[1]), pack2(h[2], h[3]));
    *(int2*)&wol[off] = make_int2(pack2(l[0], l[1]), pack2(l[2], l[3]));
  } else {
    const int n4 = NB * NS * ND / 4;
    for (int i = (blk - 16896) * 256 + tid; i < n4; i += 2048 * 256) {
      float4 v = ((const float4*)x)[i];
      short h0, l0, h1, l1, h2, l2, h3, l3;
      split_bf16(v.x, h0, l0);
      split_bf16(v.y, h1, l1);
      split_bf16(v.z, h2, l2);
      split_bf16(v.w, h3, l3);
      ((int2*)xh)[i] = make_int2(pack2(h0, h1), pack2(h2, h3));
      ((int2*)xl)[i] = make_int2(pack2(l0, l1), pack2(l2, l3));
    }
  }
}

// ---------------------------------------------------------------------------
// Standalone prep kernels (fallback paths; validated round-8 versions).
// ---------------------------------------------------------------------------
__global__ __launch_bounds__(256) void rope_table_kernel(float2* tab) {
  const int id = blockIdx.x * 256 + threadIdx.x;  // 131072 total
  const int spos = id >> 6, p = id & 63;
  const float invf = powf(10000.f, -(float)p * (1.f / 64.f));
  float s, c;
  sincosf((float)spos * invf, &s, &c);
  tab[id] = make_float2(c, s);
}

__global__ __launch_bounds__(256) void transpose_split_kernel(
    const float* __restrict__ W, short* __restrict__ Th, short* __restrict__ Tl,
    int K, int N) {
  __shared__ float T[32][33];
  const int tid = threadIdx.x;
  const int n0 = blockIdx.x * 32, k0 = blockIdx.y * 32;
  {
    const int r = tid >> 3, c4 = (tid & 7) << 2;
    float4 v = *(const float4*)&W[(size_t)(k0 + r) * N + n0 + c4];
    T[r][c4 + 0] = v.x;
    T[r][c4 + 1] = v.y;
    T[r][c4 + 2] = v.z;
    T[r][c4 + 3] = v.w;
  }
  __syncthreads();
  const int n = tid >> 3, k4 = (tid & 7) << 2;
  short h[4], l[4];
#pragma unroll
  for (int e = 0; e < 4; ++e) split_bf16(T[k4 + e][n], h[e], l[e]);
  const size_t off = (size_t)(n0 + n) * K + k0 + k4;
  *(int2*)&Th[off] = make_int2(pack2(h[0], h[1]), pack2(h[2], h[3]));
  *(int2*)&Tl[off] = make_int2(pack2(l[0], l[1]), pack2(l[2], l[3]));
}

// ---------------------------------------------------------------------------
// Split-bf16 MFMA GEMM, 128x128 (round-15 validated single-buffer core).
// SPLITC: write output as bf16 hi/lo pair (RoPE applied in fp32 first) —
// feeds attention's SPLITIN path. Otherwise fp32 C.
// ---------------------------------------------------------------------------
template <bool ROPE, bool ASPLIT, bool SPLITC, int CHX, int CHY>
__global__ __launch_bounds__(256) void gemm_bf16x3_kernel(
    const float* __restrict__ Af, const short* __restrict__ Ahg,
    const short* __restrict__ Alg, const short* __restrict__ BTh,
    const short* __restrict__ BTl, float* __restrict__ C,
    short* __restrict__ Ch, short* __restrict__ Cl, int M, int N, int K,
    const float2* __restrict__ rope_tab) {
  __shared__ short Ah[128][40], Al[128][40];
  __shared__ short Bh[128][40], Bl[128][40];
  const int tid = threadIdx.x;
  const int wave = tid >> 6, lane = tid & 63;
  const int g = lane >> 4, r = lane & 15;
  const int wy = wave >> 1, wx = wave & 1;

  int bx = blockIdx.x, by = blockIdx.y;
  if (CHX > 0) {  // XCD-aware 2D chunk swizzle (bijective)
    const int flat = by * gridDim.x + bx;
    const int xcd = flat & 7, idx = flat >> 3;
    bx = (xcd & 3) * CHX + idx % CHX;
    by = (xcd >> 2) * CHY + idx / CHX;
  }
  const int m0 = by * 128, n0 = bx * 128;
  const int wm = wy * 64, wn = wx * 64;

  const int ar = tid >> 1, ac = (tid & 1) << 4;

  const short* bhp = BTh + (size_t)(n0 + ar) * K + ac;
  const short* blp = BTl + (size_t)(n0 + ar) * K + ac;

  float4v acc[4][4];
#pragma unroll
  for (int i = 0; i < 4; ++i)
#pragma unroll
    for (int j = 0; j < 4; ++j) acc[i][j] = (float4v){0.f, 0.f, 0.f, 0.f};

  float4 a0, a1, a2, a3;
  int4 ah0, ah1, al0, al1;
  const float* aptr = nullptr;
  const short* ahp = nullptr;
  const short* alp = nullptr;
  if (ASPLIT) {
    ahp = Ahg + (size_t)(m0 + ar) * K + ac;
    alp = Alg + (size_t)(m0 + ar) * K + ac;
    ah0 = *(const int4*)(ahp);
    ah1 = *(const int4*)(ahp + 8);
    al0 = *(const int4*)(alp);
    al1 = *(const int4*)(alp + 8);
  } else {
    aptr = Af + (size_t)(m0 + ar) * K + ac;
    a0 = *(const float4*)(aptr);
    a1 = *(const float4*)(aptr + 4);
    a2 = *(const float4*)(aptr + 8);
    a3 = *(const float4*)(aptr + 12);
  }
  int4 bh0 = *(const int4*)(bhp);
  int4 bh1 = *(const int4*)(bhp + 8);
  int4 bl0 = *(const int4*)(blp);
  int4 bl1 = *(const int4*)(blp + 8);

  for (int k0 = 0; k0 < K; k0 += 32) {
    __syncthreads();  // previous chunk consumed
    if (ASPLIT) {
      *(int4*)&Ah[ar][ac] = ah0;
      *(int4*)&Ah[ar][ac + 8] = ah1;
      *(int4*)&Al[ar][ac] = al0;
      *(int4*)&Al[ar][ac + 8] = al1;
    } else {
      float xs[16] = {a0.x, a0.y, a0.z, a0.w, a1.x, a1.y, a1.z, a1.w,
                      a2.x, a2.y, a2.z, a2.w, a3.x, a3.y, a3.z, a3.w};
      short h[16], l[16];
#pragma unroll
      for (int e = 0; e < 16; ++e) split_bf16(xs[e], h[e], l[e]);
      *(int4*)&Ah[ar][ac] =
          make_int4(pack2(h[0], h[1]), pack2(h[2], h[3]), pack2(h[4], h[5]),
                    pack2(h[6], h[7]));
      *(int4*)&Ah[ar][ac + 8] =
          make_int4(pack2(h[8], h[9]), pack2(h[10], h[11]),
                    pack2(h[12], h[13]), pack2(h[14], h[15]));
      *(int4*)&Al[ar][ac] =
          make_int4(pack2(l[0], l[1]), pack2(l[2], l[3]), pack2(l[4], l[5]),
                    pack2(l[6], l[7]));
      *(int4*)&Al[ar][ac + 8] =
          make_int4(pack2(l[8], l[9]), pack2(l[10], l[11]),
                    pack2(l[12], l[13]), pack2(l[14], l[15]));
    }
    *(int4*)&Bh[ar][ac] = bh0;
    *(int4*)&Bh[ar][ac + 8] = bh1;
    *(int4*)&Bl[ar][ac] = bl0;
    *(int4*)&Bl[ar][ac + 8] = bl1;
    __syncthreads();
    if (k0 + 32 < K) {  // prefetch next chunk
      if (ASPLIT) {
        ah0 = *(const int4*)(ahp + k0 + 32);
        ah1 = *(const int4*)(ahp + k0 + 40);
        al0 = *(const int4*)(alp + k0 + 32);
        al1 = *(const int4*)(alp + k0 + 40);
      } else {
        const float* an = aptr + k0 + 32;
        a0 = *(const float4*)(an);
        a1 = *(const float4*)(an + 4);
        a2 = *(const float4*)(an + 8);
        a3 = *(const float4*)(an + 12);
      }
      bh0 = *(const int4*)(bhp + k0 + 32);
      bh1 = *(const int4*)(bhp + k0 + 40);
      bl0 = *(const int4*)(blp + k0 + 32);
      bl1 = *(const int4*)(blp + k0 + 40);
    }
    // fragments + MFMA
    short8v afh[4], afl[4], bfh[4], bfl[4];
#pragma unroll
    for (int mi = 0; mi < 4; ++mi) {
      afh[mi] = *(const short8v*)&Ah[wm + mi * 16 + r][8 * g];
      afl[mi] = *(const short8v*)&Al[wm + mi * 16 + r][8 * g];
    }
#pragma unroll
    for (int nj = 0; nj < 4; ++nj) {
      bfh[nj] = *(const short8v*)&Bh[wn + nj * 16 + r][8 * g];
      bfl[nj] = *(const short8v*)&Bl[wn + nj * 16 + r][8 * g];
    }
#pragma unroll
    for (int mi = 0; mi < 4; ++mi)
#pragma unroll
      for (int nj = 0; nj < 4; ++nj) {
        acc[mi][nj] = MFMA16(afh[mi], bfh[nj], acc[mi][nj]);
        acc[mi][nj] = MFMA16(afh[mi], bfl[nj], acc[mi][nj]);
        acc[mi][nj] = MFMA16(afl[mi], bfh[nj], acc[mi][nj]);
      }
  }

  if (ROPE && n0 < 2 * ND) {  // q,k slabs only (v passthrough)
    int p[4];
#pragma unroll
    for (int nj = 0; nj < 4; ++nj)
      p[nj] = ((n0 + wn + nj * 16 + r) & (HD - 1)) >> 1;
    const bool even = (r & 1) == 0;
#pragma unroll
    for (int mi = 0; mi < 4; ++mi)
#pragma unroll
      for (int j = 0; j < 4; ++j) {
        const int spos = (m0 + wm + mi * 16 + 4 * g + j) & (NS - 1);
#pragma unroll
        for (int nj = 0; nj < 4; ++nj) {
          const float2 cs = rope_tab[spos * 64 + p[nj]];
          const float own = acc[mi][nj][j];
          const float oth = __shfl_xor(own, 1);
          acc[mi][nj][j] = even ? own * cs.x - oth * cs.y
                                : oth * cs.y + own * cs.x;
        }
      }
  }
#pragma unroll
  for (int mi = 0; mi < 4; ++mi)
#pragma unroll
    for (int j = 0; j < 4; ++j) {
      const size_t row = m0 + wm + mi * 16 + 4 * g + j;
      if (SPLITC) {
        short* Chr = Ch + row * N + n0 + wn;
        short* Clr = Cl + row * N + n0 + wn;
#pragma unroll
        for (int nj = 0; nj < 4; ++nj) {
          short h_, l_;
          split_bf16(acc[mi][nj][j], h_, l_);
          Chr[nj * 16 + r] = h_;
          Clr[nj * 16 + r] = l_;
        }
      } else {
        float* Crow = C + row * N + n0 + wn;
#pragma unroll
        for (int nj = 0; nj < 4; ++nj) Crow[nj * 16 + r] = acc[mi][nj][j];
      }
    }
}

// ---------------------------------------------------------------------------
// Fallback tiled fp32 GEMM (validated round-5/6 kernel, unchanged).
// ---------------------------------------------------------------------------
template <bool ROPE>
__global__ __launch_bounds__(256) void gemm_f32_kernel(
    const float* __restrict__ A, const float* __restrict__ Bm,
    float* __restrict__ C, int M, int N, int K) {
  __shared__ float As[16][132];
  __shared__ float Bs[16][132];
  const int tid = threadIdx.x;
  const int m0 = blockIdx.y * 128;
  const int n0 = blockIdx.x * 128;
  const int tr = tid >> 4;
  const int tc = tid & 15;
  const int la_r = tid >> 1;
  const int la_c = (tid & 1) << 3;
  const int lb_r = tid >> 4;
  const int lb_c = (tid & 15) << 3;

  const float* Aptr = A + (size_t)(m0 + la_r) * K + la_c;
  const float* Bptr = Bm + (size_t)lb_r * N + n0 + lb_c;

  float acc[8][8] = {};

  float4 av0 = *(const float4*)(Aptr);
  float4 av1 = *(const float4*)(Aptr + 4);
  float4 bv0 = *(const float4*)(Bptr);
  float4 bv1 = *(const float4*)(Bptr + 4);

  for (int k0 = 0; k0 < K; k0 += 16) {
    __syncthreads();
    As[la_c + 0][la_r] = av0.x;
    As[la_c + 1][la_r] = av0.y;
    As[la_c + 2][la_r] = av0.z;
    As[la_c + 3][la_r] = av0.w;
    As[la_c + 4][la_r] = av1.x;
    As[la_c + 5][la_r] = av1.y;
    As[la_c + 6][la_r] = av1.z;
    As[la_c + 7][la_r] = av1.w;
    *(float4*)&Bs[lb_r][lb_c] = bv0;
    *(float4*)&Bs[lb_r][lb_c + 4] = bv1;
    __syncthreads();
    if (k0 + 16 < K) {
      const float* An = Aptr + k0 + 16;
      const float* Bn = Bptr + (size_t)(k0 + 16) * N;
      av0 = *(const float4*)(An);
      av1 = *(const float4*)(An + 4);
      bv0 = *(const float4*)(Bn);
      bv1 = *(const float4*)(Bn + 4);
    }
#pragma unroll
    for (int kk = 0; kk < 16; ++kk) {
      float a[8], b[8];
      *(float4*)&a[0] = *(const float4*)&As[kk][tr << 2];
      *(float4*)&a[4] = *(const float4*)&As[kk][64 + (tr << 2)];
      *(float4*)&b[0] = *(const float4*)&Bs[kk][tc << 2];
      *(float4*)&b[4] = *(const float4*)&Bs[kk][64 + (tc << 2)];
#pragma unroll
      for (int i = 0; i < 8; ++i)
#pragma unroll
        for (int j = 0; j < 8; ++j) acc[i][j] = fmaf(a[i], b[j], acc[i][j]);
    }
  }

  if (ROPE) {
    if ((n0 >> 11) < 2) {
#pragma unroll
      for (int g = 0; g < 2; ++g) {
        const int col = n0 + g * 64 + (tc << 2);
        const int d0 = col & (HD - 1);
        const int p0 = d0 >> 1;
        const float invf0 = powf(10000.f, -(float)p0 * (1.f / 64.f));
        const float invf1 = powf(10000.f, -(float)(p0 + 1) * (1.f / 64.f));
#pragma unroll
        for (int rg = 0; rg < 2; ++rg) {
#pragma unroll
          for (int i = 0; i < 4; ++i) {
            const int row = m0 + rg * 64 + (tr << 2) + i;
            const int spos = row & (NS - 1);
            float s0, c0, s1, c1;
            sincosf((float)spos * invf0, &s0, &c0);
            sincosf((float)spos * invf1, &s1, &c1);
            float* ar2 = &acc[rg * 4 + i][g * 4];
            const float xe0 = ar2[0], xo0 = ar2[1];
            const float xe1 = ar2[2], xo1 = ar2[3];
            ar2[0] = xe0 * c0 - xo0 * s0;
            ar2[1] = xe0 * s0 + xo0 * c0;
            ar2[2] = xe1 * c1 - xo1 * s1;
            ar2[3] = xe1 * s1 + xo1 * c1;
          }
        }
      }
    }
  }
#pragma unroll
  for (int rg = 0; rg < 2; ++rg) {
#pragma unroll
    for (int i = 0; i < 4; ++i) {
      const size_t row = m0 + rg * 64 + (tr << 2) + i;
      float* Crow = C + row * N + n0;
      float4 v0 = make_float4(acc[rg * 4 + i][0], acc[rg * 4 + i][1],
                              acc[rg * 4 + i][2], acc[rg * 4 + i][3]);
      float4 v1 = make_float4(acc[rg * 4 + i][4], acc[rg * 4 + i][5],
                              acc[rg * 4 + i][6], acc[rg * 4 + i][7]);
      *(float4*)(Crow + (tc << 2)) = v0;
      *(float4*)(Crow + 64 + (tc << 2)) = v1;
    }
  }
}

// ---------------------------------------------------------------------------
// Flash attention via split-bf16 MFMA (round-13 validated core).
// SPLITIN: qkv arrives pre-split (qkvh/qkvl bf16); staging becomes pure
// copies (no split VALU); 1/sqrt(hd) scale folded into S (fp32, post-MFMA).
// SPLITOUT: write output as bf16 hi/lo (validated round 13).
// ---------------------------------------------------------------------------
template <bool SPLITIN, bool SPLITOUT>
__global__ __launch_bounds__(512) void flash_attn_mfma(
    const float* __restrict__ qkv, const short* __restrict__ qkvh,
    const short* __restrict__ qkvl, float* __restrict__ O,
    short* __restrict__ Oh, short* __restrict__ Ol) {
  __shared__ short Khi[32][136];
  __shared__ short Klo[32][136];
  __shared__ short Vthi[128][40];
  __shared__ short Vtlo[128][40];
  __shared__ short Phi[8][16][40];
  __shared__ short Plo[8][16][40];

  const int tid = threadIdx.x;
  const int lane = tid & 63;
  const int wave = tid >> 6;
  const int g = lane >> 4;
  const int r = lane & 15;
  const int qtile = 15 - blockIdx.x;
  const int bh = blockIdx.y;
  const int b = bh >> 4, h = bh & 15;
  const int qb = qtile << 7;
  const int qw = qb + (wave << 4);
  const size_t row3d = 3 * ND;
  const size_t boff = (size_t)b * NS * row3d + (size_t)h * HD;
  const float* base = SPLITIN ? nullptr : qkv + boff;
  const short* baseh = SPLITIN ? qkvh + boff : nullptr;
  const short* basel = SPLITIN ? qkvl + boff : nullptr;

  const float scale = 0.088388347648318447f;
  short8v qhi[4], qlo[4];
  if (SPLITIN) {
    const size_t qoff = (size_t)(qw + r) * row3d;
#pragma unroll
    for (int hf = 0; hf < 4; ++hf) {
      qhi[hf] = *(const short8v*)&baseh[qoff + 32 * hf + 8 * g];
      qlo[hf] = *(const short8v*)&basel[qoff + 32 * hf + 8 * g];
    }
  } else {
    const float* Qrow = base + (size_t)(qw + r) * row3d;
#pragma unroll
    for (int hf = 0; hf < 4; ++hf) {
      const float* p = Qrow + 32 * hf + 8 * g;
      float4 x0 = *(const float4*)(p);
      float4 x1 = *(const float4*)(p + 4);
      float xs[8] = {x0.x, x0.y, x0.z, x0.w, x1.x, x1.y, x1.z, x1.w};
#pragma unroll
      for (int i = 0; i < 8; ++i) {
        short hi_, lo_;
        split_bf16(xs[i] * scale, hi_, lo_);
        qhi[hf][i] = hi_;
        qlo[hf][i] = lo_;
      }
    }
  }

  float4v acc[8];
#pragma unroll
  for (int i = 0; i < 8; ++i) acc[i] = (float4v){0.f, 0.f, 0.f, 0.f};
  float m_run = -INFINITY;
  float l_run = 0.f;

  const int skv = tid >> 4;
  const int shd = (tid & 15) << 3;
  const int vkv = (tid & 15) << 1;
  const int vhd = (tid >> 4) << 2;
  const int ntiles = (qtile + 1) << 2;

  for (int t = 0; t < ntiles; ++t) {
    const int kvb = t << 5;
    __syncthreads();
    if (SPLITIN) {
      {  // K: pure int4 copies (8 shorts), no split VALU
        const size_t koff = (size_t)(kvb + skv) * row3d + ND + shd;
        *(int4*)&Khi[skv][shd] = *(const int4*)&baseh[koff];
        *(int4*)&Klo[skv][shd] = *(const int4*)&basel[koff];
      }
      {  // V transposed: pack kv-pairs from pre-split rows
        const size_t voff = (size_t)(kvb + vkv) * row3d + 2 * ND + vhd;
        const short* v0h = &baseh[voff];
        const short* v1h = v0h + row3d;
        const short* v0l = &basel[voff];
        const short* v1l = v0l + row3d;
#pragma unroll
        for (int e = 0; e < 4; ++e) {
          *(int*)&Vthi[vhd + e][vkv] = pack2(v0h[e], v1h[e]);
          *(int*)&Vtlo[vhd + e][vkv] = pack2(v0l[e], v1l[e]);
        }
      }
    } else {
      {
        const float* kr = base + ND + (size_t)(kvb + skv) * row3d + shd;
#pragma unroll
        for (int u = 0; u < 2; ++u) {
          float4 v = *(const float4*)(kr + 4 * u);
          short h0, l0, h1, l1, h2, l2, h3, l3;
          split_bf16(v.x, h0, l0);
          split_bf16(v.y, h1, l1);
          split_bf16(v.z, h2, l2);
          split_bf16(v.w, h3, l3);
          *(int2*)&Khi[skv][shd + 4 * u] =
              make_int2(pack2(h0, h1), pack2(h2, h3));
          *(int2*)&Klo[skv][shd + 4 * u] =
              make_int2(pack2(l0, l1), pack2(l2, l3));
        }
      }
      {
        const float* v0p = base + 2 * ND + (size_t)(kvb + vkv) * row3d + vhd;
        const float* v1p = v0p + row3d;
        float4 a0 = *(const float4*)(v0p);
        float4 b0 = *(const float4*)(v1p);
        float e0[4] = {a0.x, a0.y, a0.z, a0.w};
        float e1[4] = {b0.x, b0.y, b0.z, b0.w};
#pragma unroll
        for (int e = 0; e < 4; ++e) {
          short h0, l0, h1, l1;
          split_bf16(e0[e], h0, l0);
          split_bf16(e1[e], h1, l1);
          *(int*)&Vthi[vhd + e][vkv] = pack2(h0, h1);
          *(int*)&Vtlo[vhd + e][vkv] = pack2(l0, l1);
        }
      }
    }
    __syncthreads();

    if (kvb <= qw + 15) {
      float4v s4[2];
#pragma unroll
      for (int f = 0; f < 2; ++f) s4[f] = (float4v){0.f, 0.f, 0.f, 0.f};
#pragma unroll
      for (int f = 0; f < 2; ++f) {
#pragma unroll
        for (int hf = 0; hf < 4; ++hf) {
          short8v ka = *(const short8v*)&Khi[16 * f + r][32 * hf + 8 * g];
          short8v kb = *(const short8v*)&Klo[16 * f + r][32 * hf + 8 * g];
          s4[f] = MFMA16(ka, qhi[hf], s4[f]);
          s4[f] = MFMA16(ka, qlo[hf], s4[f]);
          s4[f] = MFMA16(kb, qhi[hf], s4[f]);
        }
      }
      if (SPLITIN) {  // scale folded into S (Q was unscaled)
#pragma unroll
        for (int f = 0; f < 2; ++f)
#pragma unroll
          for (int j = 0; j < 4; ++j) s4[f][j] *= scale;
      }
      const int qglob = qw + r;
      if (kvb + 31 > qw) {
#pragma unroll
        for (int f = 0; f < 2; ++f)
#pragma unroll
          for (int j = 0; j < 4; ++j)
            if (kvb + 16 * f + 4 * g + j > qglob) s4[f][j] = -INFINITY;
      }
      float tmax = s4[0][0];
#pragma unroll
      for (int f = 0; f < 2; ++f)
#pragma unroll
        for (int j = 0; j < 4; ++j) tmax = fmaxf(tmax, s4[f][j]);
      tmax = fmaxf(tmax, __shfl_xor(tmax, 16));
      tmax = fmaxf(tmax, __shfl_xor(tmax, 32));
      const float mnew = fmaxf(m_run, tmax);
      const float alpha = __expf(m_run - mnew);
      float psum = 0.f;
      short ph[8], pl[8];
#pragma unroll
      for (int f = 0; f < 2; ++f)
#pragma unroll
        for (int j = 0; j < 4; ++j) {
          float p = __expf(s4[f][j] - mnew);
          psum += p;
          split_bf16(p, ph[4 * f + j], pl[4 * f + j]);
        }
      psum += __shfl_xor(psum, 16);
      psum += __shfl_xor(psum, 32);
      l_run = l_run * alpha + psum;
      m_run = mnew;
#pragma unroll
      for (int f = 0; f < 2; ++f) {
        *(int2*)&Phi[wave][r][16 * f + 4 * g] = make_int2(
            pack2(ph[4 * f + 0], ph[4 * f + 1]),
            pack2(ph[4 * f + 2], ph[4 * f + 3]));
        *(int2*)&Plo[wave][r][16 * f + 4 * g] = make_int2(
            pack2(pl[4 * f + 0], pl[4 * f + 1]),
            pack2(pl[4 * f + 2], pl[4 * f + 3]));
      }
      float aj[4];
#pragma unroll
      for (int j = 0; j < 4; ++j) aj[j] = __shfl(alpha, 4 * g + j);
#pragma unroll
      for (int hf = 0; hf < 8; ++hf)
#pragma unroll
        for (int j = 0; j < 4; ++j) acc[hf][j] *= aj[j];
      short8v pa = *(const short8v*)&Phi[wave][r][8 * g];
      short8v pb = *(const short8v*)&Plo[wave][r][8 * g];
#pragma unroll
      for (int hf = 0; hf < 8; ++hf) {
        short8v va = *(const short8v*)&Vthi[16 * hf + r][8 * g];
        short8v vb = *(const short8v*)&Vtlo[16 * hf + r][8 * g];
        acc[hf] = MFMA16(pa, va, acc[hf]);
        acc[hf] = MFMA16(pa, vb, acc[hf]);
        acc[hf] = MFMA16(pb, va, acc[hf]);
      }
    }
  }
  const float il = 1.f / l_run;
  float lj[4];
#pragma unroll
  for (int j = 0; j < 4; ++j) lj[j] = __shfl(il, 4 * g + j);
  const size_t obase = ((size_t)b * NS + qw) * ND + h * HD;
  if (SPLITOUT) {
    short* OhB = Oh + obase;
    short* OlB = Ol + obase;
#pragma unroll
    for (int hf = 0; hf < 8; ++hf)
#pragma unroll
      for (int j = 0; j < 4; ++j) {
        const float v = acc[hf][j] * lj[j];
        short h_, l_;
        split_bf16(v, h_, l_);
        const size_t idx = (size_t)(4 * g + j) * ND + 16 * hf + r;
        OhB[idx] = h_;
        OlB[idx] = l_;
      }
  } else {
    float* Ob = O + obase;
#pragma unroll
    for (int hf = 0; hf < 8; ++hf)
#pragma unroll
      for (int j = 0; j < 4; ++j)
        Ob[(size_t)(4 * g + j) * ND + 16 * hf + r] = acc[hf][j] * lj[j];
  }
}

// ---------------------------------------------------------------------------
// Launch. Full layout 225 MiB: qkvh+qkvl bf16 (reuses the fp32 qkv footprint
// exactly) | attn f32 | WqkvT hi/lo | WoT hi/lo | rope tab | xh/xl.
// ath/atl ALIAS xh/xl. Full path: fused prep -> QKV GEMM (bf16 split out,
// fused RoPE) -> attention (split in, split out) -> out GEMM. 4 launches.
// Fallbacks: base (inline-split A, fp32 qkv) -> fp32 GEMMs.
// ---------------------------------------------------------------------------
extern "C" void kernel_launch(void* const* d_in, const int* in_sizes, int n_in,
                              void* d_out, int out_size, void* d_ws,
                              size_t ws_size, hipStream_t stream) {
  const float* x = (const float*)d_in[0];
  const float* Wqkv = (const float*)d_in[1];
  const float* Wo = (const float*)d_in[2];
  float* out = (float*)d_out;
  float* qkv = (float*)d_ws;                       // 25165824 f (fallback)
  short* qkvh = (short*)d_ws;                      // 25165824 s
  short* qkvl = qkvh + (size_t)NB * NS * 3 * ND;   // 25165824 s
  float* attn = qkv + (size_t)NB * NS * 3 * ND;    // 8388608 f
  short* wqh = (short*)(attn + (size_t)NB * NS * ND);  // 12582912 s each
  short* wql = wqh + (size_t)ND * 3 * ND;
  short* woh = wql + (size_t)ND * 3 * ND;          // 4194304 s each
  short* wol = woh + (size_t)ND * ND;
  float2* tab = (float2*)(wol + (size_t)ND * ND);  // 131072 float2
  short* xh = (short*)(tab + (size_t)NS * 64);     // 8388608 s each
  short* xl = xh + (size_t)NB * NS * ND;
  short* ath = xh;  // ALIAS: x splits dead after QKV GEMM
  short* atl = xl;

  const size_t base_need =
      ((size_t)NB * NS * 3 * ND + (size_t)NB * NS * ND) * 4 +
      ((size_t)ND * 3 * ND + (size_t)ND * ND) * 2 * 2 + (size_t)NS * 64 * 8;
  const size_t full_need = base_need + (size_t)NB * NS * ND * 2 * 2;

  const int M = NB * NS;
  if (ws_size >= full_need) {
    fused_prep_kernel<<<18944, 256, 0, stream>>>(
        tab, Wqkv, wqh, wql, Wo, woh, wol, x, xh, xl);
    gemm_bf16x3_kernel<true, true, true, 12, 16>
        <<<dim3(3 * ND / 128, M / 128), 256, 0, stream>>>(
            nullptr, xh, xl, wqh, wql, nullptr, qkvh, qkvl, M, 3 * ND, ND,
            tab);
    flash_attn_mfma<true, true><<<dim3(16, 32), 512, 0, stream>>>(
        nullptr, qkvh, qkvl, nullptr, ath, atl);
    gemm_bf16x3_kernel<false, true, false, 4, 16>
        <<<dim3(ND / 128, M / 128), 256, 0, stream>>>(
            nullptr, ath, atl, woh, wol, out, nullptr, nullptr, M, ND, ND,
            tab);
  } else if (ws_size >= base_need) {
    rope_table_kernel<<<NS * 64 / 256, 256, 0, stream>>>(tab);
    transpose_split_kernel<<<dim3(3 * ND / 32, ND / 32), 256, 0, stream>>>(
        Wqkv, wqh, wql, ND, 3 * ND);
    transpose_split_kernel<<<dim3(ND / 32, ND / 32), 256, 0, stream>>>(
        Wo, woh, wol, ND, ND);
    gemm_bf16x3_kernel<true, false, false, 0, 0>
        <<<dim3(3 * ND / 128, M / 128), 256, 0, stream>>>(
            x, nullptr, nullptr, wqh, wql, qkv, nullptr, nullptr, M, 3 * ND,
            ND, tab);
    flash_attn_mfma<false, false><<<dim3(16, 32), 512, 0, stream>>>(
        qkv, nullptr, nullptr, attn, nullptr, nullptr);
    gemm_bf16x3_kernel<false, false, false, 0, 0>
        <<<dim3(ND / 128, M / 128), 256, 0, stream>>>(
            attn, nullptr, nullptr, woh, wol, out, nullptr, nullptr, M, ND,
            ND, tab);
  } else {
    gemm_f32_kernel<true>
        <<<dim3(3 * ND / 128, M / 128), 256, 0, stream>>>(
            x, Wqkv, qkv, M, 3 * ND, ND);
    flash_attn_mfma<false, false><<<dim3(16, 32), 512, 0, stream>>>(
        qkv, nullptr, nullptr, attn, nullptr, nullptr);
    gemm_f32_kernel<false>
        <<<dim3(ND / 128, M / 128), 256, 0, stream>>>(
            attn, Wo, out, M, ND, ND);
  }
}

// Round 21
// 698.771 us; speedup vs baseline: 1.0635x; 1.0635x over previous
//
#include <hip/hip_runtime.h>
#include <cstddef>
#include <cstdint>
#include <math.h>

// Problem constants (B=2, S=2048, D=2048, H=16, hd=128)
#define NB 2
#define NS 2048
#define ND 2048
#define NH 16
#define HD 128

typedef __attribute__((ext_vector_type(8))) short short8v;   // 8 bf16 (4 VGPR)
typedef __attribute__((ext_vector_type(4))) float float4v;   // MFMA acc

#define MFMA16(A, B, C) __builtin_amdgcn_mfma_f32_16x16x32_bf16(A, B, C, 0, 0, 0)

// Split fp32 into bf16 hi + bf16 lo (x ~= hi + lo, rel err ~2^-17).
__device__ __forceinline__ void split_bf16(float x, short& hi, short& lo) {
  unsigned u = __float_as_uint(x);
  unsigned hb = (u + 0x7FFFu + ((u >> 16) & 1u)) >> 16;
  float hif = __uint_as_float(hb << 16);
  float r = x - hif;
  unsigned ul = __float_as_uint(r);
  hi = (short)hb;
  lo = (short)((ul + 0x7FFFu + ((ul >> 16) & 1u)) >> 16);
}

__device__ __forceinline__ int pack2(short a, short b) {
  return (int)(unsigned short)a | ((int)(unsigned short)b << 16);
}

// ---------------------------------------------------------------------------
// FUSED prep kernel (validated round-15).
// ---------------------------------------------------------------------------
__global__ __launch_bounds__(256) void fused_prep_kernel(
    float2* __restrict__ tab,
    const float* __restrict__ Wqkv, short* __restrict__ wqh,
    short* __restrict__ wql,
    const float* __restrict__ Wo, short* __restrict__ woh,
    short* __restrict__ wol,
    const float* __restrict__ x, short* __restrict__ xh,
    short* __restrict__ xl) {
  __shared__ float T[32][33];
  const int tid = threadIdx.x;
  const int blk = blockIdx.x;
  if (blk < 512) {
    const int id = blk * 256 + tid;
    const int spos = id >> 6, p = id & 63;
    const float invf = powf(10000.f, -(float)p * (1.f / 64.f));
    float s, c;
    sincosf((float)spos * invf, &s, &c);
    tab[id] = make_float2(c, s);
  } else if (blk < 12800) {
    const int t = blk - 512;
    const int n0 = (t % 192) * 32, k0 = (t / 192) * 32;
    const int K = ND, N = 3 * ND;
    {
      const int r = tid >> 3, c4 = (tid & 7) << 2;
      float4 v = *(const float4*)&Wqkv[(size_t)(k0 + r) * N + n0 + c4];
      T[r][c4 + 0] = v.x;
      T[r][c4 + 1] = v.y;
      T[r][c4 + 2] = v.z;
      T[r][c4 + 3] = v.w;
    }
    __syncthreads();
    const int n = tid >> 3, k4 = (tid & 7) << 2;
    short h[4], l[4];
#pragma unroll
    for (int e = 0; e < 4; ++e) split_bf16(T[k4 + e][n], h[e], l[e]);
    const size_t off = (size_t)(n0 + n) * K + k0 + k4;
    *(int2*)&wqh[off] = make_int2(pack2(h[0], h[1]), pack2(h[2], h[3]));
    *(int2*)&wql[off] = make_int2(pack2(l[0], l[1]), pack2(l[2], l[3]));
  } else if (blk < 16896) {
    const int t = blk - 12800;
    const int n0 = (t % 64) * 32, k0 = (t / 64) * 32;
    const int K = ND, N = ND;
    {
      const int r = tid >> 3, c4 = (tid & 7) << 2;
      float4 v = *(const float4*)&Wo[(size_t)(k0 + r) * N + n0 + c4];
      T[r][c4 + 0] = v.x;
      T[r][c4 + 1] = v.y;
      T[r][c4 + 2] = v.z;
      T[r][c4 + 3] = v.w;
    }
    __syncthreads();
    const int n = tid >> 3, k4 = (tid & 7) << 2;
    short h[4], l[4];
#pragma unroll
    for (int e = 0; e < 4; ++e) split_bf16(T[k4 + e][n], h[e], l[e]);
    const size_t off = (size_t)(n0 + n) * K + k0 + k4;
    *(int2*)&woh[off] = make_int2(pack2(h[0], h[1]), pack2(h[2], h[3]));
    *(int2*)&wol[off] = make_int2(pack2(l[0], l[1]), pack2(l[2], l[3]));
  } else {
    const int n4 = NB * NS * ND / 4;
    for (int i = (blk - 16896) * 256 + tid; i < n4; i += 2048 * 256) {
      float4 v = ((const float4*)x)[i];
      short h0, l0, h1, l1, h2, l2, h3, l3;
      split_bf16(v.x, h0, l0);
      split_bf16(v.y, h1, l1);
      split_bf16(v.z, h2, l2);
      split_bf16(v.w, h3, l3);
      ((int2*)xh)[i] = make_int2(pack2(h0, h1), pack2(h2, h3));
      ((int2*)xl)[i] = make_int2(pack2(l0, l1), pack2(l2, l3));
    }
  }
}

// ---------------------------------------------------------------------------
// Standalone prep kernels (fallback paths; validated round-8 versions).
// ---------------------------------------------------------------------------
__global__ __launch_bounds__(256) void rope_table_kernel(float2* tab) {
  const int id = blockIdx.x * 256 + threadIdx.x;  // 131072 total
  const int spos = id >> 6, p = id & 63;
  const float invf = powf(10000.f, -(float)p * (1.f / 64.f));
  float s, c;
  sincosf((float)spos * invf, &s, &c);
  tab[id] = make_float2(c, s);
}

__global__ __launch_bounds__(256) void transpose_split_kernel(
    const float* __restrict__ W, short* __restrict__ Th, short* __restrict__ Tl,
    int K, int N) {
  __shared__ float T[32][33];
  const int tid = threadIdx.x;
  const int n0 = blockIdx.x * 32, k0 = blockIdx.y * 32;
  {
    const int r = tid >> 3, c4 = (tid & 7) << 2;
    float4 v = *(const float4*)&W[(size_t)(k0 + r) * N + n0 + c4];
    T[r][c4 + 0] = v.x;
    T[r][c4 + 1] = v.y;
    T[r][c4 + 2] = v.z;
    T[r][c4 + 3] = v.w;
  }
  __syncthreads();
  const int n = tid >> 3, k4 = (tid & 7) << 2;
  short h[4], l[4];
#pragma unroll
  for (int e = 0; e < 4; ++e) split_bf16(T[k4 + e][n], h[e], l[e]);
  const size_t off = (size_t)(n0 + n) * K + k0 + k4;
  *(int2*)&Th[off] = make_int2(pack2(h[0], h[1]), pack2(h[2], h[3]));
  *(int2*)&Tl[off] = make_int2(pack2(l[0], l[1]), pack2(l[2], l[3]));
}

// ---------------------------------------------------------------------------
// QKV GEMM, 256x128 tile (round-19 validated): C[M,N] = A @ BT, A pre-split
// [M][K] bf16 hi/lo, BT pre-split [N][K]. 512 thr = 8 waves (4x2), each wave
// 64x64 (4x4 16x16 frags), BK=32, single-buffered LDS (60 KB).
// Fused RoPE epilogue. XCD swizzle for grid (48,16): chunks 12x8, bijective.
// ---------------------------------------------------------------------------
__global__ __launch_bounds__(512) void gemm_bf16x3_256(
    const short* __restrict__ Ahg, const short* __restrict__ Alg,
    const short* __restrict__ BTh, const short* __restrict__ BTl,
    float* __restrict__ C, int M, int N, int K,
    const float2* __restrict__ rope_tab) {
  __shared__ short Ah[256][40], Al[256][40];
  __shared__ short Bh[128][40], Bl[128][40];
  const int tid = threadIdx.x;
  const int wave = tid >> 6, lane = tid & 63;
  const int g = lane >> 4, r = lane & 15;
  const int wy = wave >> 1, wx = wave & 1;

  int bx = blockIdx.x, by = blockIdx.y;
  {  // XCD swizzle: 8 XCDs as 4x2, chunks 12x8 (48x16 grid, 96 blocks/XCD)
    const int flat = by * gridDim.x + bx;
    const int xcd = flat & 7, idx = flat >> 3;
    bx = (xcd & 3) * 12 + idx % 12;
    by = (xcd >> 2) * 8 + idx / 12;
  }
  const int m0 = by * 256, n0 = bx * 128;
  const int wm = wy * 64, wn = wx * 64;

  // staging maps
  const int ar = tid >> 1, ac = (tid & 1) << 4;  // A: 256 rows, 16 shorts
  const int br = tid >> 2, bc = (tid & 3) << 3;  // B: 128 rows, 8 shorts

  const short* ahp = Ahg + (size_t)(m0 + ar) * K + ac;
  const short* alp = Alg + (size_t)(m0 + ar) * K + ac;
  const short* bhp = BTh + (size_t)(n0 + br) * K + bc;
  const short* blp = BTl + (size_t)(n0 + br) * K + bc;

  float4v acc[4][4];
#pragma unroll
  for (int i = 0; i < 4; ++i)
#pragma unroll
    for (int j = 0; j < 4; ++j) acc[i][j] = (float4v){0.f, 0.f, 0.f, 0.f};

  // prologue: chunk 0 loads
  int4 ah0 = *(const int4*)(ahp);
  int4 ah1 = *(const int4*)(ahp + 8);
  int4 al0 = *(const int4*)(alp);
  int4 al1 = *(const int4*)(alp + 8);
  int4 bh0 = *(const int4*)(bhp);
  int4 bl0 = *(const int4*)(blp);

  for (int k0 = 0; k0 < K; k0 += 32) {
    __syncthreads();  // previous chunk consumed
    *(int4*)&Ah[ar][ac] = ah0;
    *(int4*)&Ah[ar][ac + 8] = ah1;
    *(int4*)&Al[ar][ac] = al0;
    *(int4*)&Al[ar][ac + 8] = al1;
    *(int4*)&Bh[br][bc] = bh0;
    *(int4*)&Bl[br][bc] = bl0;
    __syncthreads();
    if (k0 + 32 < K) {  // prefetch next chunk
      ah0 = *(const int4*)(ahp + k0 + 32);
      ah1 = *(const int4*)(ahp + k0 + 40);
      al0 = *(const int4*)(alp + k0 + 32);
      al1 = *(const int4*)(alp + k0 + 40);
      bh0 = *(const int4*)(bhp + k0 + 32);
      bl0 = *(const int4*)(blp + k0 + 32);
    }
    // fragments + MFMA
    short8v afh[4], afl[4], bfh[4], bfl[4];
#pragma unroll
    for (int mi = 0; mi < 4; ++mi) {
      afh[mi] = *(const short8v*)&Ah[wm + mi * 16 + r][8 * g];
      afl[mi] = *(const short8v*)&Al[wm + mi * 16 + r][8 * g];
    }
#pragma unroll
    for (int nj = 0; nj < 4; ++nj) {
      bfh[nj] = *(const short8v*)&Bh[wn + nj * 16 + r][8 * g];
      bfl[nj] = *(const short8v*)&Bl[wn + nj * 16 + r][8 * g];
    }
#pragma unroll
    for (int mi = 0; mi < 4; ++mi)
#pragma unroll
      for (int nj = 0; nj < 4; ++nj) {
        acc[mi][nj] = MFMA16(afh[mi], bfh[nj], acc[mi][nj]);
        acc[mi][nj] = MFMA16(afh[mi], bfl[nj], acc[mi][nj]);
        acc[mi][nj] = MFMA16(afl[mi], bfh[nj], acc[mi][nj]);
      }
  }

  if (n0 < 2 * ND) {  // RoPE on q,k slabs (v passthrough)
    int p[4];
#pragma unroll
    for (int nj = 0; nj < 4; ++nj)
      p[nj] = ((n0 + wn + nj * 16 + r) & (HD - 1)) >> 1;
    const bool even = (r & 1) == 0;
#pragma unroll
    for (int mi = 0; mi < 4; ++mi)
#pragma unroll
      for (int j = 0; j < 4; ++j) {
        const int spos = (m0 + wm + mi * 16 + 4 * g + j) & (NS - 1);
#pragma unroll
        for (int nj = 0; nj < 4; ++nj) {
          const float2 cs = rope_tab[spos * 64 + p[nj]];
          const float own = acc[mi][nj][j];
          const float oth = __shfl_xor(own, 1);
          acc[mi][nj][j] = even ? own * cs.x - oth * cs.y
                                : oth * cs.y + own * cs.x;
        }
      }
  }
#pragma unroll
  for (int mi = 0; mi < 4; ++mi)
#pragma unroll
    for (int j = 0; j < 4; ++j) {
      const size_t row = m0 + wm + mi * 16 + 4 * g + j;
      float* Crow = C + row * N + n0 + wn;
#pragma unroll
      for (int nj = 0; nj < 4; ++nj) Crow[nj * 16 + r] = acc[mi][nj][j];
    }
}

// ---------------------------------------------------------------------------
// Split-bf16 MFMA GEMM, 128x128 (round-15 VALIDATED single-buffer version).
// ---------------------------------------------------------------------------
template <bool ROPE, bool ASPLIT, int CHX, int CHY>
__global__ __launch_bounds__(256) void gemm_bf16x3_kernel(
    const float* __restrict__ Af, const short* __restrict__ Ahg,
    const short* __restrict__ Alg, const short* __restrict__ BTh,
    const short* __restrict__ BTl, float* __restrict__ C, int M, int N, int K,
    const float2* __restrict__ rope_tab) {
  __shared__ short Ah[128][40], Al[128][40];
  __shared__ short Bh[128][40], Bl[128][40];
  const int tid = threadIdx.x;
  const int wave = tid >> 6, lane = tid & 63;
  const int g = lane >> 4, r = lane & 15;
  const int wy = wave >> 1, wx = wave & 1;

  int bx = blockIdx.x, by = blockIdx.y;
  if (CHX > 0) {  // XCD-aware 2D chunk swizzle (bijective)
    const int flat = by * gridDim.x + bx;
    const int xcd = flat & 7, idx = flat >> 3;
    bx = (xcd & 3) * CHX + idx % CHX;
    by = (xcd >> 2) * CHY + idx / CHX;
  }
  const int m0 = by * 128, n0 = bx * 128;
  const int wm = wy * 64, wn = wx * 64;

  const int ar = tid >> 1, ac = (tid & 1) << 4;

  const short* bhp = BTh + (size_t)(n0 + ar) * K + ac;
  const short* blp = BTl + (size_t)(n0 + ar) * K + ac;

  float4v acc[4][4];
#pragma unroll
  for (int i = 0; i < 4; ++i)
#pragma unroll
    for (int j = 0; j < 4; ++j) acc[i][j] = (float4v){0.f, 0.f, 0.f, 0.f};

  float4 a0, a1, a2, a3;
  int4 ah0, ah1, al0, al1;
  const float* aptr = nullptr;
  const short* ahp = nullptr;
  const short* alp = nullptr;
  if (ASPLIT) {
    ahp = Ahg + (size_t)(m0 + ar) * K + ac;
    alp = Alg + (size_t)(m0 + ar) * K + ac;
    ah0 = *(const int4*)(ahp);
    ah1 = *(const int4*)(ahp + 8);
    al0 = *(const int4*)(alp);
    al1 = *(const int4*)(alp + 8);
  } else {
    aptr = Af + (size_t)(m0 + ar) * K + ac;
    a0 = *(const float4*)(aptr);
    a1 = *(const float4*)(aptr + 4);
    a2 = *(const float4*)(aptr + 8);
    a3 = *(const float4*)(aptr + 12);
  }
  int4 bh0 = *(const int4*)(bhp);
  int4 bh1 = *(const int4*)(bhp + 8);
  int4 bl0 = *(const int4*)(blp);
  int4 bl1 = *(const int4*)(blp + 8);

  for (int k0 = 0; k0 < K; k0 += 32) {
    __syncthreads();  // previous chunk consumed
    if (ASPLIT) {
      *(int4*)&Ah[ar][ac] = ah0;
      *(int4*)&Ah[ar][ac + 8] = ah1;
      *(int4*)&Al[ar][ac] = al0;
      *(int4*)&Al[ar][ac + 8] = al1;
    } else {
      float xs[16] = {a0.x, a0.y, a0.z, a0.w, a1.x, a1.y, a1.z, a1.w,
                      a2.x, a2.y, a2.z, a2.w, a3.x, a3.y, a3.z, a3.w};
      short h[16], l[16];
#pragma unroll
      for (int e = 0; e < 16; ++e) split_bf16(xs[e], h[e], l[e]);
      *(int4*)&Ah[ar][ac] =
          make_int4(pack2(h[0], h[1]), pack2(h[2], h[3]), pack2(h[4], h[5]),
                    pack2(h[6], h[7]));
      *(int4*)&Ah[ar][ac + 8] =
          make_int4(pack2(h[8], h[9]), pack2(h[10], h[11]),
                    pack2(h[12], h[13]), pack2(h[14], h[15]));
      *(int4*)&Al[ar][ac] =
          make_int4(pack2(l[0], l[1]), pack2(l[2], l[3]), pack2(l[4], l[5]),
                    pack2(l[6], l[7]));
      *(int4*)&Al[ar][ac + 8] =
          make_int4(pack2(l[8], l[9]), pack2(l[10], l[11]),
                    pack2(l[12], l[13]), pack2(l[14], l[15]));
    }
    *(int4*)&Bh[ar][ac] = bh0;
    *(int4*)&Bh[ar][ac + 8] = bh1;
    *(int4*)&Bl[ar][ac] = bl0;
    *(int4*)&Bl[ar][ac + 8] = bl1;
    __syncthreads();
    if (k0 + 32 < K) {  // prefetch next chunk
      if (ASPLIT) {
        ah0 = *(const int4*)(ahp + k0 + 32);
        ah1 = *(const int4*)(ahp + k0 + 40);
        al0 = *(const int4*)(alp + k0 + 32);
        al1 = *(const int4*)(alp + k0 + 40);
      } else {
        const float* an = aptr + k0 + 32;
        a0 = *(const float4*)(an);
        a1 = *(const float4*)(an + 4);
        a2 = *(const float4*)(an + 8);
        a3 = *(const float4*)(an + 12);
      }
      bh0 = *(const int4*)(bhp + k0 + 32);
      bh1 = *(const int4*)(bhp + k0 + 40);
      bl0 = *(const int4*)(blp + k0 + 32);
      bl1 = *(const int4*)(blp + k0 + 40);
    }
    // fragments + MFMA
    short8v afh[4], afl[4], bfh[4], bfl[4];
#pragma unroll
    for (int mi = 0; mi < 4; ++mi) {
      afh[mi] = *(const short8v*)&Ah[wm + mi * 16 + r][8 * g];
      afl[mi] = *(const short8v*)&Al[wm + mi * 16 + r][8 * g];
    }
#pragma unroll
    for (int nj = 0; nj < 4; ++nj) {
      bfh[nj] = *(const short8v*)&Bh[wn + nj * 16 + r][8 * g];
      bfl[nj] = *(const short8v*)&Bl[wn + nj * 16 + r][8 * g];
    }
#pragma unroll
    for (int mi = 0; mi < 4; ++mi)
#pragma unroll
      for (int nj = 0; nj < 4; ++nj) {
        acc[mi][nj] = MFMA16(afh[mi], bfh[nj], acc[mi][nj]);
        acc[mi][nj] = MFMA16(afh[mi], bfl[nj], acc[mi][nj]);
        acc[mi][nj] = MFMA16(afl[mi], bfh[nj], acc[mi][nj]);
      }
  }

  if (ROPE && n0 < 2 * ND) {  // q,k slabs only (v passthrough)
    int p[4];
#pragma unroll
    for (int nj = 0; nj < 4; ++nj)
      p[nj] = ((n0 + wn + nj * 16 + r) & (HD - 1)) >> 1;
    const bool even = (r & 1) == 0;
#pragma unroll
    for (int mi = 0; mi < 4; ++mi)
#pragma unroll
      for (int j = 0; j < 4; ++j) {
        const int spos = (m0 + wm + mi * 16 + 4 * g + j) & (NS - 1);
#pragma unroll
        for (int nj = 0; nj < 4; ++nj) {
          const float2 cs = rope_tab[spos * 64 + p[nj]];
          const float own = acc[mi][nj][j];
          const float oth = __shfl_xor(own, 1);
          acc[mi][nj][j] = even ? own * cs.x - oth * cs.y
                                : oth * cs.y + own * cs.x;
        }
      }
  }
#pragma unroll
  for (int mi = 0; mi < 4; ++mi)
#pragma unroll
    for (int j = 0; j < 4; ++j) {
      const size_t row = m0 + wm + mi * 16 + 4 * g + j;
      float* Crow = C + row * N + n0 + wn;
#pragma unroll
      for (int nj = 0; nj < 4; ++nj) Crow[nj * 16 + r] = acc[mi][nj][j];
    }
}

// ---------------------------------------------------------------------------
// Fallback tiled fp32 GEMM (validated round-5/6 kernel, unchanged).
// ---------------------------------------------------------------------------
template <bool ROPE>
__global__ __launch_bounds__(256) void gemm_f32_kernel(
    const float* __restrict__ A, const float* __restrict__ Bm,
    float* __restrict__ C, int M, int N, int K) {
  __shared__ float As[16][132];
  __shared__ float Bs[16][132];
  const int tid = threadIdx.x;
  const int m0 = blockIdx.y * 128;
  const int n0 = blockIdx.x * 128;
  const int tr = tid >> 4;
  const int tc = tid & 15;
  const int la_r = tid >> 1;
  const int la_c = (tid & 1) << 3;
  const int lb_r = tid >> 4;
  const int lb_c = (tid & 15) << 3;

  const float* Aptr = A + (size_t)(m0 + la_r) * K + la_c;
  const float* Bptr = Bm + (size_t)lb_r * N + n0 + lb_c;

  float acc[8][8] = {};

  float4 av0 = *(const float4*)(Aptr);
  float4 av1 = *(const float4*)(Aptr + 4);
  float4 bv0 = *(const float4*)(Bptr);
  float4 bv1 = *(const float4*)(Bptr + 4);

  for (int k0 = 0; k0 < K; k0 += 16) {
    __syncthreads();
    As[la_c + 0][la_r] = av0.x;
    As[la_c + 1][la_r] = av0.y;
    As[la_c + 2][la_r] = av0.z;
    As[la_c + 3][la_r] = av0.w;
    As[la_c + 4][la_r] = av1.x;
    As[la_c + 5][la_r] = av1.y;
    As[la_c + 6][la_r] = av1.z;
    As[la_c + 7][la_r] = av1.w;
    *(float4*)&Bs[lb_r][lb_c] = bv0;
    *(float4*)&Bs[lb_r][lb_c + 4] = bv1;
    __syncthreads();
    if (k0 + 16 < K) {
      const float* An = Aptr + k0 + 16;
      const float* Bn = Bptr + (size_t)(k0 + 16) * N;
      av0 = *(const float4*)(An);
      av1 = *(const float4*)(An + 4);
      bv0 = *(const float4*)(Bn);
      bv1 = *(const float4*)(Bn + 4);
    }
#pragma unroll
    for (int kk = 0; kk < 16; ++kk) {
      float a[8], b[8];
      *(float4*)&a[0] = *(const float4*)&As[kk][tr << 2];
      *(float4*)&a[4] = *(const float4*)&As[kk][64 + (tr << 2)];
      *(float4*)&b[0] = *(const float4*)&Bs[kk][tc << 2];
      *(float4*)&b[4] = *(const float4*)&Bs[kk][64 + (tc << 2)];
#pragma unroll
      for (int i = 0; i < 8; ++i)
#pragma unroll
        for (int j = 0; j < 8; ++j) acc[i][j] = fmaf(a[i], b[j], acc[i][j]);
    }
  }

  if (ROPE) {
    if ((n0 >> 11) < 2) {
#pragma unroll
      for (int g = 0; g < 2; ++g) {
        const int col = n0 + g * 64 + (tc << 2);
        const int d0 = col & (HD - 1);
        const int p0 = d0 >> 1;
        const float invf0 = powf(10000.f, -(float)p0 * (1.f / 64.f));
        const float invf1 = powf(10000.f, -(float)(p0 + 1) * (1.f / 64.f));
#pragma unroll
        for (int rg = 0; rg < 2; ++rg) {
#pragma unroll
          for (int i = 0; i < 4; ++i) {
            const int row = m0 + rg * 64 + (tr << 2) + i;
            const int spos = row & (NS - 1);
            float s0, c0, s1, c1;
            sincosf((float)spos * invf0, &s0, &c0);
            sincosf((float)spos * invf1, &s1, &c1);
            float* ar2 = &acc[rg * 4 + i][g * 4];
            const float xe0 = ar2[0], xo0 = ar2[1];
            const float xe1 = ar2[2], xo1 = ar2[3];
            ar2[0] = xe0 * c0 - xo0 * s0;
            ar2[1] = xe0 * s0 + xo0 * c0;
            ar2[2] = xe1 * c1 - xo1 * s1;
            ar2[3] = xe1 * s1 + xo1 * c1;
          }
        }
      }
    }
  }
#pragma unroll
  for (int rg = 0; rg < 2; ++rg) {
#pragma unroll
    for (int i = 0; i < 4; ++i) {
      const size_t row = m0 + rg * 64 + (tr << 2) + i;
      float* Crow = C + row * N + n0;
      float4 v0 = make_float4(acc[rg * 4 + i][0], acc[rg * 4 + i][1],
                              acc[rg * 4 + i][2], acc[rg * 4 + i][3]);
      float4 v1 = make_float4(acc[rg * 4 + i][4], acc[rg * 4 + i][5],
                              acc[rg * 4 + i][6], acc[rg * 4 + i][7]);
      *(float4*)(Crow + (tc << 2)) = v0;
      *(float4*)(Crow + 64 + (tc << 2)) = v1;
    }
  }
}

// ---------------------------------------------------------------------------
// Flash attention via split-bf16 MFMA (validated round-13 kernel, unchanged).
// ---------------------------------------------------------------------------
template <bool SPLITOUT>
__global__ __launch_bounds__(512) void flash_attn_mfma(
    const float* __restrict__ qkv, float* __restrict__ O,
    short* __restrict__ Oh, short* __restrict__ Ol) {
  __shared__ short Khi[32][136];
  __shared__ short Klo[32][136];
  __shared__ short Vthi[128][40];
  __shared__ short Vtlo[128][40];
  __shared__ short Phi[8][16][40];
  __shared__ short Plo[8][16][40];

  const int tid = threadIdx.x;
  const int lane = tid & 63;
  const int wave = tid >> 6;
  const int g = lane >> 4;
  const int r = lane & 15;
  const int qtile = 15 - blockIdx.x;
  const int bh = blockIdx.y;
  const int b = bh >> 4, h = bh & 15;
  const int qb = qtile << 7;
  const int qw = qb + (wave << 4);
  const size_t row3d = 3 * ND;
  const float* base = qkv + (size_t)b * NS * row3d + (size_t)h * HD;
  const float* Kg = base + ND;
  const float* Vg = base + 2 * ND;

  const float scale = 0.088388347648318447f;
  const float* Qrow = base + (size_t)(qw + r) * row3d;
  short8v qhi[4], qlo[4];
#pragma unroll
  for (int hf = 0; hf < 4; ++hf) {
    const float* p = Qrow + 32 * hf + 8 * g;
    float4 x0 = *(const float4*)(p);
    float4 x1 = *(const float4*)(p + 4);
    float xs[8] = {x0.x, x0.y, x0.z, x0.w, x1.x, x1.y, x1.z, x1.w};
#pragma unroll
    for (int i = 0; i < 8; ++i) {
      short hi_, lo_;
      split_bf16(xs[i] * scale, hi_, lo_);
      qhi[hf][i] = hi_;
      qlo[hf][i] = lo_;
    }
  }

  float4v acc[8];
#pragma unroll
  for (int i = 0; i < 8; ++i) acc[i] = (float4v){0.f, 0.f, 0.f, 0.f};
  float m_run = -INFINITY;
  float l_run = 0.f;

  const int skv = tid >> 4;
  const int shd = (tid & 15) << 3;
  const int vkv = (tid & 15) << 1;
  const int vhd = (tid >> 4) << 2;
  const int ntiles = (qtile + 1) << 2;

  for (int t = 0; t < ntiles; ++t) {
    const int kvb = t << 5;
    __syncthreads();
    {
      const float* kr = Kg + (size_t)(kvb + skv) * row3d + shd;
#pragma unroll
      for (int u = 0; u < 2; ++u) {
        float4 v = *(const float4*)(kr + 4 * u);
        short h0, l0, h1, l1, h2, l2, h3, l3;
        split_bf16(v.x, h0, l0);
        split_bf16(v.y, h1, l1);
        split_bf16(v.z, h2, l2);
        split_bf16(v.w, h3, l3);
        *(int2*)&Khi[skv][shd + 4 * u] =
            make_int2(pack2(h0, h1), pack2(h2, h3));
        *(int2*)&Klo[skv][shd + 4 * u] =
            make_int2(pack2(l0, l1), pack2(l2, l3));
      }
    }
    {
      const float* v0p = Vg + (size_t)(kvb + vkv) * row3d + vhd;
      const float* v1p = v0p + row3d;
      float4 a0 = *(const float4*)(v0p);
      float4 b0 = *(const float4*)(v1p);
      float e0[4] = {a0.x, a0.y, a0.z, a0.w};
      float e1[4] = {b0.x, b0.y, b0.z, b0.w};
#pragma unroll
      for (int e = 0; e < 4; ++e) {
        short h0, l0, h1, l1;
        split_bf16(e0[e], h0, l0);
        split_bf16(e1[e], h1, l1);
        *(int*)&Vthi[vhd + e][vkv] = pack2(h0, h1);
        *(int*)&Vtlo[vhd + e][vkv] = pack2(l0, l1);
      }
    }
    __syncthreads();

    if (kvb <= qw + 15) {
      float4v s4[2];
#pragma unroll
      for (int f = 0; f < 2; ++f) s4[f] = (float4v){0.f, 0.f, 0.f, 0.f};
#pragma unroll
      for (int f = 0; f < 2; ++f) {
#pragma unroll
        for (int hf = 0; hf < 4; ++hf) {
          short8v ka = *(const short8v*)&Khi[16 * f + r][32 * hf + 8 * g];
          short8v kb = *(const short8v*)&Klo[16 * f + r][32 * hf + 8 * g];
          s4[f] = MFMA16(ka, qhi[hf], s4[f]);
          s4[f] = MFMA16(ka, qlo[hf], s4[f]);
          s4[f] = MFMA16(kb, qhi[hf], s4[f]);
        }
      }
      const int qglob = qw + r;
      if (kvb + 31 > qw) {
#pragma unroll
        for (int f = 0; f < 2; ++f)
#pragma unroll
          for (int j = 0; j < 4; ++j)
            if (kvb + 16 * f + 4 * g + j > qglob) s4[f][j] = -INFINITY;
      }
      float tmax = s4[0][0];
#pragma unroll
      for (int f = 0; f < 2; ++f)
#pragma unroll
        for (int j = 0; j < 4; ++j) tmax = fmaxf(tmax, s4[f][j]);
      tmax = fmaxf(tmax, __shfl_xor(tmax, 16));
      tmax = fmaxf(tmax, __shfl_xor(tmax, 32));
      const float mnew = fmaxf(m_run, tmax);
      const float alpha = __expf(m_run - mnew);
      float psum = 0.f;
      short ph[8], pl[8];
#pragma unroll
      for (int f = 0; f < 2; ++f)
#pragma unroll
        for (int j = 0; j < 4; ++j) {
          float p = __expf(s4[f][j] - mnew);
          psum += p;
          split_bf16(p, ph[4 * f + j], pl[4 * f + j]);
        }
      psum += __shfl_xor(psum, 16);
      psum += __shfl_xor(psum, 32);
      l_run = l_run * alpha + psum;
      m_run = mnew;
#pragma unroll
      for (int f = 0; f < 2; ++f) {
        *(int2*)&Phi[wave][r][16 * f + 4 * g] = make_int2(
            pack2(ph[4 * f + 0], ph[4 * f + 1]),
            pack2(ph[4 * f + 2], ph[4 * f + 3]));
        *(int2*)&Plo[wave][r][16 * f + 4 * g] = make_int2(
            pack2(pl[4 * f + 0], pl[4 * f + 1]),
            pack2(pl[4 * f + 2], pl[4 * f + 3]));
      }
      float aj[4];
#pragma unroll
      for (int j = 0; j < 4; ++j) aj[j] = __shfl(alpha, 4 * g + j);
#pragma unroll
      for (int hf = 0; hf < 8; ++hf)
#pragma unroll
        for (int j = 0; j < 4; ++j) acc[hf][j] *= aj[j];
      short8v pa = *(const short8v*)&Phi[wave][r][8 * g];
      short8v pb = *(const short8v*)&Plo[wave][r][8 * g];
#pragma unroll
      for (int hf = 0; hf < 8; ++hf) {
        short8v va = *(const short8v*)&Vthi[16 * hf + r][8 * g];
        short8v vb = *(const short8v*)&Vtlo[16 * hf + r][8 * g];
        acc[hf] = MFMA16(pa, va, acc[hf]);
        acc[hf] = MFMA16(pa, vb, acc[hf]);
        acc[hf] = MFMA16(pb, va, acc[hf]);
      }
    }
  }
  const float il = 1.f / l_run;
  float lj[4];
#pragma unroll
  for (int j = 0; j < 4; ++j) lj[j] = __shfl(il, 4 * g + j);
  const size_t obase = ((size_t)b * NS + qw) * ND + h * HD;
  if (SPLITOUT) {
    short* OhB = Oh + obase;
    short* OlB = Ol + obase;
#pragma unroll
    for (int hf = 0; hf < 8; ++hf)
#pragma unroll
      for (int j = 0; j < 4; ++j) {
        const float v = acc[hf][j] * lj[j];
        short h_, l_;
        split_bf16(v, h_, l_);
        const size_t idx = (size_t)(4 * g + j) * ND + 16 * hf + r;
        OhB[idx] = h_;
        OlB[idx] = l_;
      }
  } else {
    float* Ob = O + obase;
#pragma unroll
    for (int hf = 0; hf < 8; ++hf)
#pragma unroll
      for (int j = 0; j < 4; ++j)
        Ob[(size_t)(4 * g + j) * ND + 16 * hf + r] = acc[hf][j] * lj[j];
  }
}

// ---------------------------------------------------------------------------
// Launch. Full layout 225 MiB. Full path: fused prep -> 256x128 QKV GEMM ->
// attention (bf16 split out) -> 128^2 out GEMM. Fallbacks: base (inline-split
// A, 128^2) -> fp32 GEMMs.
// ---------------------------------------------------------------------------
extern "C" void kernel_launch(void* const* d_in, const int* in_sizes, int n_in,
                              void* d_out, int out_size, void* d_ws,
                              size_t ws_size, hipStream_t stream) {
  const float* x = (const float*)d_in[0];
  const float* Wqkv = (const float*)d_in[1];
  const float* Wo = (const float*)d_in[2];
  float* out = (float*)d_out;
  float* qkv = (float*)d_ws;                       // 25165824 f
  float* attn = qkv + (size_t)NB * NS * 3 * ND;    // 8388608 f
  short* wqh = (short*)(attn + (size_t)NB * NS * ND);  // 12582912 s each
  short* wql = wqh + (size_t)ND * 3 * ND;
  short* woh = wql + (size_t)ND * 3 * ND;          // 4194304 s each
  short* wol = woh + (size_t)ND * ND;
  float2* tab = (float2*)(wol + (size_t)ND * ND);  // 131072 float2
  short* xh = (short*)(tab + (size_t)NS * 64);     // 8388608 s each
  short* xl = xh + (size_t)NB * NS * ND;
  short* ath = xh;  // ALIAS: x splits dead after QKV GEMM
  short* atl = xl;

  const size_t base_need =
      ((size_t)NB * NS * 3 * ND + (size_t)NB * NS * ND) * 4 +
      ((size_t)ND * 3 * ND + (size_t)ND * ND) * 2 * 2 + (size_t)NS * 64 * 8;
  const size_t full_need = base_need + (size_t)NB * NS * ND * 2 * 2;

  const int M = NB * NS;
  if (ws_size >= full_need) {
    fused_prep_kernel<<<18944, 256, 0, stream>>>(
        tab, Wqkv, wqh, wql, Wo, woh, wol, x, xh, xl);
    gemm_bf16x3_256<<<dim3(3 * ND / 128, M / 256), 512, 0, stream>>>(
        xh, xl, wqh, wql, qkv, M, 3 * ND, ND, tab);
    flash_attn_mfma<true><<<dim3(16, 32), 512, 0, stream>>>(
        qkv, nullptr, ath, atl);
    gemm_bf16x3_kernel<false, true, 4, 16>
        <<<dim3(ND / 128, M / 128), 256, 0, stream>>>(
            nullptr, ath, atl, woh, wol, out, M, ND, ND, tab);
  } else if (ws_size >= base_need) {
    rope_table_kernel<<<NS * 64 / 256, 256, 0, stream>>>(tab);
    transpose_split_kernel<<<dim3(3 * ND / 32, ND / 32), 256, 0, stream>>>(
        Wqkv, wqh, wql, ND, 3 * ND);
    transpose_split_kernel<<<dim3(ND / 32, ND / 32), 256, 0, stream>>>(
        Wo, woh, wol, ND, ND);
    gemm_bf16x3_kernel<true, false, 0, 0>
        <<<dim3(3 * ND / 128, M / 128), 256, 0, stream>>>(
            x, nullptr, nullptr, wqh, wql, qkv, M, 3 * ND, ND, tab);
    flash_attn_mfma<false><<<dim3(16, 32), 512, 0, stream>>>(
        qkv, attn, nullptr, nullptr);
    gemm_bf16x3_kernel<false, false, 0, 0>
        <<<dim3(ND / 128, M / 128), 256, 0, stream>>>(
            attn, nullptr, nullptr, woh, wol, out, M, ND, ND, tab);
  } else {
    gemm_f32_kernel<true>
        <<<dim3(3 * ND / 128, M / 128), 256, 0, stream>>>(
            x, Wqkv, qkv, M, 3 * ND, ND);
    flash_attn_mfma<false><<<dim3(16, 32), 512, 0, stream>>>(
        qkv, attn, nullptr, nullptr);
    gemm_f32_kernel<false>
        <<<dim3(ND / 128, M / 128), 256, 0, stream>>>(
            attn, Wo, out, M, ND, ND);
  }
}